// Round 1
// baseline (143.735 us; speedup 1.0000x reference)
//
#include <hip/hip_runtime.h>
#include <hip/hip_bf16.h>
#include <math.h>

// Problem constants (fixed by setup_inputs)
#define NB      2      // batch
#define T_IN    12
#define T_OUT_  24
#define O_OUT   12     // T_OUT - T_IN
#define NN      10000  // nodes
#define CC      16     // channels
#define KK      17     // neighbors
#define HH      4      // heads
#define JJ      48     // T_IN * HH

// ---------------- sigma = max(nearest_dists) ----------------
__global__ void sigma_reduce_kernel(const float* __restrict__ d, int n,
                                    unsigned int* __restrict__ out) {
    float m = 0.0f;  // dists are uniform [0,1): non-negative
    for (int i = blockIdx.x * blockDim.x + threadIdx.x; i < n;
         i += gridDim.x * blockDim.x)
        m = fmaxf(m, d[i]);
    // wave (64-lane) reduce
    #pragma unroll
    for (int off = 32; off > 0; off >>= 1)
        m = fmaxf(m, __shfl_down(m, off, 64));
    __shared__ float sm[8];
    int lane = threadIdx.x & 63, wid = threadIdx.x >> 6;
    if (lane == 0) sm[wid] = m;
    __syncthreads();
    if (threadIdx.x == 0) {
        float mm = sm[0];
        int nw = (blockDim.x + 63) >> 6;
        for (int w = 1; w < nw; ++w) mm = fmaxf(mm, sm[w]);
        // non-negative floats: uint bit pattern is order-preserving
        atomicMax(out, __float_as_uint(mm));
    }
}

// ---------------- main fused kernel: one block per node ----------------
__global__ __launch_bounds__(384) void gnn_extrap_kernel(
    const float* __restrict__ x,          // (B, T_IN, N, C)
    const int*   __restrict__ nodes,      // (N, K)
    const float* __restrict__ dists,      // (N, K)
    const float* __restrict__ Wm,         // (O_OUT, J)
    const float* __restrict__ bias,       // (O_OUT,)
    const unsigned int* __restrict__ sigma_bits,
    float* __restrict__ out)              // (B, T_OUT, N, C)
{
    const int n   = blockIdx.x;
    const int tid = threadIdx.x;

    __shared__ float w_s[KK][HH];
    __shared__ int   idx_s[KK];
    __shared__ float a_s[NB * JJ * CC];   // [b][j][c], j = t*H + h  (6 KB)
    __shared__ float W_s[O_OUT * JJ];     // 2.25 KB
    __shared__ float b_s[O_OUT];

    const float sigma   = __uint_as_float(*sigma_bits);
    const float inv_s2  = 1.0f / (sigma * sigma);

    if (tid < KK) {
        int nd = nodes[n * KK + tid];
        idx_s[tid] = (nd < 0) ? 0 : nd;   // w==0 kills the contribution
    }
    if (tid < KK * HH) {
        const int k = tid / HH, h = tid % HH;
        const int   nd = nodes[n * KK + k];
        const float dd = dists[n * KK + k];
        const float lam = (float)(h + 1) * (1.0f / (float)HH);
        float w = expf(-dd * dd * lam * inv_s2);
        if (nd == -1 || w < 1e-8f) w = 0.0f;
        w_s[k][h] = w;
    }
    for (int i = tid; i < O_OUT * JJ; i += blockDim.x) W_s[i] = Wm[i];
    if (tid < O_OUT) b_s[tid] = bias[tid];
    __syncthreads();

    // ---- Phase B: gather + aggregate. thread = (b, t, c) ----
    const int c  = tid & 15;
    const int bt = tid >> 4;        // 0..23
    const int t  = bt % T_IN;
    const int b  = bt / T_IN;
    const long xbase = (long)(b * T_IN + t) * NN * CC;

    float acc0 = 0.f, acc1 = 0.f, acc2 = 0.f, acc3 = 0.f;
    #pragma unroll
    for (int k = 0; k < KK; ++k) {
        const float g = x[xbase + (long)idx_s[k] * CC + c];
        acc0 += g * w_s[k][0];
        acc1 += g * w_s[k][1];
        acc2 += g * w_s[k][2];
        acc3 += g * w_s[k][3];
    }

    // passthrough: out[b, t, n, c] = x[b, t, n, c]
    const float xv = x[xbase + (long)n * CC + c];
    out[(long)(b * T_OUT_ + t) * NN * CC + (long)n * CC + c] = xv;

    // a_s[b][j][c] with j = t*H + h
    const int ja = (b * JJ + t * HH) * CC + c;
    a_s[ja + 0 * CC] = acc0;
    a_s[ja + 1 * CC] = acc1;
    a_s[ja + 2 * CC] = acc2;
    a_s[ja + 3 * CC] = acc3;
    __syncthreads();

    // ---- Phase C: y[b,o,c] = selu(sum_j a[b,j,c] * W[o,j] + bias[o]) ----
    const int c2   = tid & 15;
    const int rest = tid >> 4;      // 0..23
    const int o    = rest % O_OUT;
    const int b2   = rest / O_OUT;

    float y = b_s[o];
    #pragma unroll
    for (int j = 0; j < JJ; ++j)
        y += a_s[(b2 * JJ + j) * CC + c2] * W_s[o * JJ + j];

    const float kScale = 1.0507009873554805f;
    const float kAlpha = 1.6732632423543772f;
    y = (y > 0.0f) ? kScale * y : kScale * kAlpha * expm1f(y);

    out[(long)(b2 * T_OUT_ + T_IN + o) * NN * CC + (long)n * CC + c2] = y;
}

extern "C" void kernel_launch(void* const* d_in, const int* in_sizes, int n_in,
                              void* d_out, int out_size, void* d_ws, size_t ws_size,
                              hipStream_t stream) {
    const float* x     = (const float*)d_in[0];
    const int*   nodes = (const int*)  d_in[1];
    const float* dists = (const float*)d_in[2];
    const float* Wm    = (const float*)d_in[3];
    const float* bias  = (const float*)d_in[4];
    float* out = (float*)d_out;
    unsigned int* sigma_bits = (unsigned int*)d_ws;

    // d_ws is poisoned to 0xAA each call; zero the sigma slot (capture-safe)
    hipMemsetAsync(d_ws, 0, sizeof(unsigned int), stream);

    const int nd = in_sizes[2];  // N*K = 170000
    sigma_reduce_kernel<<<256, 256, 0, stream>>>(dists, nd, sigma_bits);

    gnn_extrap_kernel<<<NN, 384, 0, stream>>>(x, nodes, dists, Wm, bias,
                                              sigma_bits, out);
}